// Round 2
// baseline (496.002 us; speedup 1.0000x reference)
//
#include <hip/hip_runtime.h>
#include <math.h>

#define N_TOK 16384
#define DIM   2048
#define NE    64
#define TOPK  9

#define ROWS     32            // rows per block
#define DC       32            // D-chunk per K-iteration
#define NTHREADS 128
#define NWAVES   2
#define RPW      16            // rows per wave
#define NCHUNK   (DIM / DC)    // 64

#define XS_F   (ROWS * DC)     // 1024 floats (4 KB)
#define W_F    (DC * NE)       // 2048 floats (8 KB)
#define BUF_F  (XS_F + 2 * W_F) // 5120 floats (20 KB) per buffer
#define WR_OFF XS_F
#define WN_OFF (XS_F + W_F)

// async global->LDS, 16B per lane; lds base must be wave-uniform (HW writes base + lane*16)
__device__ __forceinline__ void async16(const float* g, float* l) {
    __builtin_amdgcn_global_load_lds(
        (const __attribute__((address_space(1))) void*)g,
        (__attribute__((address_space(3))) void*)l,
        16, 0, 0);
}

__device__ __forceinline__ float wave_max64(float v) {
#pragma unroll
    for (int off = 32; off > 0; off >>= 1)
        v = fmaxf(v, __shfl_xor(v, off, 64));
    return v;
}
__device__ __forceinline__ float wave_sum64(float v) {
#pragma unroll
    for (int off = 32; off > 0; off >>= 1)
        v += __shfl_xor(v, off, 64);
    return v;
}

__global__ __launch_bounds__(NTHREADS, 2)
void moe_router_kernel(const float* __restrict__ x,
                       const float* __restrict__ Wr,
                       const float* __restrict__ br,
                       const float* __restrict__ Wn,
                       const float* __restrict__ bn,
                       const float* __restrict__ noise_eps,
                       const float* __restrict__ gumbel,
                       float* __restrict__ out)
{
    __shared__ __align__(16) float buf[2][BUF_F];   // 40 KB double-buffered

    const int t    = threadIdx.x;
    const int lane = t & 63;
    const int wv   = t >> 6;                 // 0..1
    const int row0 = blockIdx.x * ROWS;

    // ---- staging descriptors (1 KB per wave-load: lds slot base uniform per wave) ----
    // x region: 4 slots; wave wv owns slots {wv, wv+2}; slot s = rows 8s..8s+7
    const float* gx[2];
    int lxo[2];
#pragma unroll
    for (int j = 0; j < 2; ++j) {
        const int s = wv + 2 * j;
        gx[j]  = x + (size_t)(row0 + 8 * s + (lane >> 3)) * DIM + (lane & 7) * 4;
        lxo[j] = s * 256;                    // float offset inside buffer
    }
    // W regions: 8 slots each; wave wv owns slots {wv, wv+2, wv+4, wv+6}; slot s = d-rows 4s..4s+3
    const float* gwr[4];
    const float* gwn[4];
    int lwo[4];
#pragma unroll
    for (int j = 0; j < 4; ++j) {
        const int s = wv + 2 * j;
        gwr[j] = Wr + (size_t)(4 * s + (lane >> 4)) * NE + (lane & 15) * 4;
        gwn[j] = Wn + (size_t)(4 * s + (lane >> 4)) * NE + (lane & 15) * 4;
        lwo[j] = s * 256;
    }

    float accr[RPW], accn[RPW];
#pragma unroll
    for (int r = 0; r < RPW; ++r) { accr[r] = 0.f; accn[r] = 0.f; }

    // ---- issue chunk 0 into buf[0] ----
#pragma unroll
    for (int j = 0; j < 2; ++j) { async16(gx[j], &buf[0][lxo[j]]); gx[j] += DC; }
#pragma unroll
    for (int j = 0; j < 4; ++j) {
        async16(gwr[j], &buf[0][WR_OFF + lwo[j]]); gwr[j] += DC * NE;
        async16(gwn[j], &buf[0][WN_OFF + lwo[j]]); gwn[j] += DC * NE;
    }

    for (int ch = 0; ch < NCHUNK; ++ch) {
        __syncthreads();   // drains vmcnt -> buf[ch&1] ready; prev compute on buf[ch^1] done
        const int b = ch & 1;
        if (ch + 1 < NCHUNK) {   // issue next chunk into the just-freed buffer
#pragma unroll
            for (int j = 0; j < 2; ++j) { async16(gx[j], &buf[b ^ 1][lxo[j]]); gx[j] += DC; }
#pragma unroll
            for (int j = 0; j < 4; ++j) {
                async16(gwr[j], &buf[b ^ 1][WR_OFF + lwo[j]]); gwr[j] += DC * NE;
                async16(gwn[j], &buf[b ^ 1][WN_OFF + lwo[j]]); gwn[j] += DC * NE;
            }
        }
        const float* xb  = &buf[b][wv * RPW * DC];
        const float* wrb = &buf[b][WR_OFF];
        const float* wnb = &buf[b][WN_OFF];
#pragma unroll 2
        for (int d4 = 0; d4 < DC / 4; ++d4) {
            const int db = d4 * 4;
            const float wr0 = wrb[(db + 0) * NE + lane];
            const float wr1 = wrb[(db + 1) * NE + lane];
            const float wr2 = wrb[(db + 2) * NE + lane];
            const float wr3 = wrb[(db + 3) * NE + lane];
            const float wn0 = wnb[(db + 0) * NE + lane];
            const float wn1 = wnb[(db + 1) * NE + lane];
            const float wn2 = wnb[(db + 2) * NE + lane];
            const float wn3 = wnb[(db + 3) * NE + lane];
#pragma unroll
            for (int r = 0; r < RPW; ++r) {
                const float4 xv = *(const float4*)&xb[r * DC + db];
                accr[r] = fmaf(xv.x, wr0, accr[r]);
                accr[r] = fmaf(xv.y, wr1, accr[r]);
                accr[r] = fmaf(xv.z, wr2, accr[r]);
                accr[r] = fmaf(xv.w, wr3, accr[r]);
                accn[r] = fmaf(xv.x, wn0, accn[r]);
                accn[r] = fmaf(xv.y, wn1, accn[r]);
                accn[r] = fmaf(xv.z, wn2, accn[r]);
                accn[r] = fmaf(xv.w, wn3, accn[r]);
            }
        }
    }

    // ---------------- epilogue: per-row wave ops (lane = expert) ----------------
    const float br_l = br[lane];
    const float bn_l = bn[lane];
    float imp_acc = 0.f, load_acc = 0.f;
    float* out_em   = out;
    float* out_rp   = out + (size_t)N_TOK * NE;
    float* out_imp  = out + (size_t)2 * N_TOK * NE;
    float* out_load = out_imp + NE;

#pragma unroll 1
    for (int r = 0; r < RPW; ++r) {
        const int row = row0 + wv * RPW + r;
        const float raw = accr[r] + br_l;
        const float nl  = accn[r] + bn_l;
        // softplus(nl) + EPS, numerically stable
        const float sd = fmaxf(nl, 0.f) + log1pf(expf(-fabsf(nl))) + 0.01f;
        const float epsv = noise_eps[(size_t)row * NE + lane];
        const float gum  = gumbel  [(size_t)row * NE + lane];
        const float noisy = fmaf(epsv, sd, raw);

        // top-9 threshold across the wave
        float cur = noisy;
        float thr = 0.f, m0 = 0.f;
#pragma unroll 1
        for (int k = 0; k < TOPK; ++k) {
            const float m = wave_max64(cur);
            if (k == 0) m0 = m;
            thr = m;
            const unsigned long long bm = __ballot(cur == m);
            const int first = __ffsll(bm) - 1;
            if (lane == first) cur = -INFINITY;
        }
        const float hard = (noisy >= thr) ? 1.f : 0.f;

        // expert_mask = (hard - ms) + ms, ms = softmax(noisy + gumbel)
        const float g  = noisy + gum;
        const float eg = expf(g - wave_max64(g));
        const float ms = eg / wave_sum64(eg);
        const float em = (hard - ms) + ms;

        // route_prob = softmax(noisy)
        const float en = expf(noisy - m0);
        const float rp = en / wave_sum64(en);

        // importance partial: softmax(raw)
        const float er = expf(raw - wave_max64(raw));
        imp_acc += er / wave_sum64(er);

        // load partial: 0.5*erfc(((thr - raw)/sd) * E/sqrt(2))
        const float z = (thr - raw) / sd;
        load_acc += 0.5f * erfcf(z * 45.254833995939045f);

        out_em[(size_t)row * NE + lane] = em;
        out_rp[(size_t)row * NE + lane] = rp;
    }

    // block reduction for importance/load: reuse staging LDS (main loop is done)
    __syncthreads();
    float* red_imp  = &buf[0][0];
    float* red_load = &buf[0][NWAVES * NE];
    red_imp [wv * NE + lane] = imp_acc;
    red_load[wv * NE + lane] = load_acc;
    __syncthreads();
    if (wv == 0) {
        float s1 = 0.f, s2 = 0.f;
#pragma unroll
        for (int i = 0; i < NWAVES; ++i) {
            s1 += red_imp [i * NE + lane];
            s2 += red_load[i * NE + lane];
        }
        atomicAdd(&out_imp [lane], s1);
        atomicAdd(&out_load[lane], s2);
    }
}

extern "C" void kernel_launch(void* const* d_in, const int* in_sizes, int n_in,
                              void* d_out, int out_size, void* d_ws, size_t ws_size,
                              hipStream_t stream)
{
    const float* x         = (const float*)d_in[0];
    const float* Wr        = (const float*)d_in[1];
    const float* br        = (const float*)d_in[2];
    const float* Wn        = (const float*)d_in[3];
    const float* bn        = (const float*)d_in[4];
    const float* noise_eps = (const float*)d_in[5];
    const float* gumbel    = (const float*)d_in[6];
    float* out = (float*)d_out;

    // importance/load are atomically accumulated — zero them (d_out is poisoned 0xAA)
    hipMemsetAsync((char*)d_out + (size_t)2 * N_TOK * NE * sizeof(float), 0,
                   2 * NE * sizeof(float), stream);

    moe_router_kernel<<<N_TOK / ROWS, NTHREADS, 0, stream>>>(
        x, Wr, br, Wn, bn, noise_eps, gumbel, out);
}

// Round 4
// 279.453 us; speedup vs baseline: 1.7749x; 1.7749x over previous
//
#include <hip/hip_runtime.h>
#include <hip/hip_bf16.h>
#include <math.h>

#define N_TOK 16384
#define DIM   2048
#define NE    64
#define TOPK  9

#define ROWS     64            // rows per block
#define DC       64            // k-elements per chunk
#define NCHUNK   (DIM / DC)    // 32
#define NTHREADS 256           // 4 waves

typedef short  short8  __attribute__((ext_vector_type(8)));
typedef float  float4_ __attribute__((ext_vector_type(4)));
typedef unsigned short ushort_t;

// LDS per buffer: [0,4096) x-tile fp32 (64 rows x 64 k, xor-swizzled granules)
//                 [4096,12288) W bf16: 32 slots x 1KB, slot = (kc_local*8+ct)*2+t
#define BUF_F 12288

__device__ __forceinline__ void async16(const void* g, void* l) {
    __builtin_amdgcn_global_load_lds(
        (const __attribute__((address_space(1))) void*)g,
        (__attribute__((address_space(3))) void*)l, 16, 0, 0);
}

__device__ __forceinline__ unsigned pk2(float a, float b) {
    float2 f; f.x = a; f.y = b;
    __hip_bfloat162 h = __float22bfloat162_rn(f);   // low16 = bf16(a), high16 = bf16(b)
    unsigned u;
    __builtin_memcpy(&u, &h, 4);
    return u;
}

// 8 fp32 -> bf16 hi frag + bf16 lo frag (2-term split)
__device__ __forceinline__ void cvt8(const float4_ va, const float4_ vb,
                                     short8* h, short8* l) {
    union { short8 s; unsigned u[4]; } H, L;
    const float f[8] = {va[0], va[1], va[2], va[3], vb[0], vb[1], vb[2], vb[3]};
#pragma unroll
    for (int i = 0; i < 4; ++i) {
        const float a = f[2 * i], b = f[2 * i + 1];
        const unsigned p = pk2(a, b);
        H.u[i] = p;
        const float ha = __uint_as_float(p << 16);
        const float hb = __uint_as_float(p & 0xffff0000u);
        L.u[i] = pk2(a - ha, b - hb);
    }
    *h = H.s; *l = L.s;
}

__device__ __forceinline__ float wave_max64(float v) {
#pragma unroll
    for (int off = 32; off > 0; off >>= 1)
        v = fmaxf(v, __shfl_xor(v, off, 64));
    return v;
}
__device__ __forceinline__ float wave_sum64(float v) {
#pragma unroll
    for (int off = 32; off > 0; off >>= 1)
        v += __shfl_xor(v, off, 64);
    return v;
}

// ---- prep: convert Wr|Wn (fp32, D x 64 each) into B-fragment-ordered bf16 hi/lo ----
// ws slot s=(kc*8+ct)*2+t holds 512 bf16: element l*8+j = B[k=kc*32+(l>>4)*8+j][n=ct*16+(l&15)]
__global__ __launch_bounds__(256)
void prep_w(const float* __restrict__ Wr, const float* __restrict__ Wn,
            ushort_t* __restrict__ wsW)
{
    const int gid = blockIdx.x * 256 + threadIdx.x;   // [0, 64*8*64*8)
    const int j  = gid & 7;
    const int l  = (gid >> 3) & 63;
    const int ct = (gid >> 9) & 7;
    const int kc = gid >> 12;                         // 0..63
    const int k  = kc * 32 + (l >> 4) * 8 + j;
    const int n  = ct * 16 + (l & 15);
    const float v = (n < NE) ? Wr[k * NE + n] : Wn[k * NE + (n - NE)];
    const unsigned uv = __float_as_uint(v);
    const unsigned hb = (uv + 0x7fffu + ((uv >> 16) & 1u)) & 0xffff0000u;
    const float lo = v - __uint_as_float(hb);
    const unsigned ul = __float_as_uint(lo);
    const unsigned lb = (ul + 0x7fffu + ((ul >> 16) & 1u)) >> 16;
    const size_t s0 = (size_t)(kc * 8 + ct) * 2;
    wsW[s0 * 512 + l * 8 + j]       = (ushort_t)(hb >> 16);
    wsW[(s0 + 1) * 512 + l * 8 + j] = (ushort_t)lb;
}

__global__ __launch_bounds__(NTHREADS, 1)
void moe_main(const float* __restrict__ x,
              const float* __restrict__ br,
              const float* __restrict__ bn,
              const float* __restrict__ noise_eps,
              const float* __restrict__ gumbel,
              const ushort_t* __restrict__ wsW,
              float* __restrict__ out)
{
    __shared__ __align__(16) float smem[2][BUF_F];    // 96 KB

    const int t    = threadIdx.x;
    const int lane = t & 63;
    const int w    = t >> 6;          // wave 0..3, owns col-tiles {2w, 2w+1}
    const int c4   = lane & 15;
    const int q    = lane >> 4;
    const int row0 = blockIdx.x * ROWS;

    // x staging sources: issue i=4w+ii covers rows 4i..4i+3; lane l -> row 4i+(l>>4),
    // LDS granule p=l&15 holds global k-granule gk = p ^ (row&15)   (bank-conflict swizzle)
    const float* gxp[4];
#pragma unroll
    for (int ii = 0; ii < 4; ++ii) {
        const int r  = 16 * w + 4 * ii + q;
        const int gk = c4 ^ (r & 15);
        gxp[ii] = x + (size_t)(row0 + r) * DIM + gk * 4;
    }
    const char* wsrc = (const char*)wsW + (size_t)(w * 8) * 1024 + lane * 16;

    // A-read LDS float offsets (chunk-invariant): row m=rt*16+c4, granules (kc*8+q*2)^c4, +1^c4
    int aoff[2][2];
#pragma unroll
    for (int kc = 0; kc < 2; ++kc) {
        const int g0 = kc * 8 + q * 2;
        aoff[kc][0] = c4 * 64 + ((g0 ^ c4) * 4);
        aoff[kc][1] = c4 * 64 + (((g0 + 1) ^ c4) * 4);
    }

    float4_ acc[4][2];
#pragma unroll
    for (int rt = 0; rt < 4; ++rt)
#pragma unroll
        for (int cc = 0; cc < 2; ++cc)
            acc[rt][cc] = (float4_)(0.f);

    // issue chunk 0 into buf0
    {
        float* xb = &smem[0][0];
        char*  wb = (char*)&smem[0][4096];
#pragma unroll
        for (int ii = 0; ii < 4; ++ii) async16(gxp[ii], xb + (4 * w + ii) * 256);
#pragma unroll
        for (int jj = 0; jj < 8; ++jj) async16(wsrc + jj * 1024, wb + (w * 8 + jj) * 1024);
#pragma unroll
        for (int ii = 0; ii < 4; ++ii) gxp[ii] += DC;
        wsrc += 32 * 1024;
    }

    for (int ch = 0; ch < NCHUNK; ++ch) {
        __syncthreads();               // drains vmcnt -> buf[ch&1] ready
        const int b = ch & 1;
        if (ch + 1 < NCHUNK) {         // prefetch next chunk into freed buffer
            float* xb = &smem[b ^ 1][0];
            char*  wb = (char*)&smem[b ^ 1][4096];
#pragma unroll
            for (int ii = 0; ii < 4; ++ii) async16(gxp[ii], xb + (4 * w + ii) * 256);
#pragma unroll
            for (int jj = 0; jj < 8; ++jj) async16(wsrc + jj * 1024, wb + (w * 8 + jj) * 1024);
#pragma unroll
            for (int ii = 0; ii < 4; ++ii) gxp[ii] += DC;
            wsrc += 32 * 1024;
        }
        const float* xb = &smem[b][0];
        const char*  wb = (const char*)&smem[b][4096];
#pragma unroll
        for (int kc = 0; kc < 2; ++kc) {
            short8 bhv[2], blv[2];
#pragma unroll
            for (int cc = 0; cc < 2; ++cc) {
                const int slot = (kc * 8 + (2 * w + cc)) * 2;
                bhv[cc] = *(const short8*)(wb + slot * 1024 + lane * 16);
                blv[cc] = *(const short8*)(wb + (slot + 1) * 1024 + lane * 16);
            }
#pragma unroll
            for (int rt = 0; rt < 4; ++rt) {
                const float4_ va = *(const float4_*)(xb + aoff[kc][0] + rt * 1024);
                const float4_ vb = *(const float4_*)(xb + aoff[kc][1] + rt * 1024);
                short8 ah, al;
                cvt8(va, vb, &ah, &al);
#pragma unroll
                for (int cc = 0; cc < 2; ++cc) {
                    acc[rt][cc] = __builtin_amdgcn_mfma_f32_16x16x32_bf16(ah, bhv[cc], acc[rt][cc], 0, 0, 0);
                    acc[rt][cc] = __builtin_amdgcn_mfma_f32_16x16x32_bf16(al, bhv[cc], acc[rt][cc], 0, 0, 0);
                    acc[rt][cc] = __builtin_amdgcn_mfma_f32_16x16x32_bf16(ah, blv[cc], acc[rt][cc], 0, 0, 0);
                }
            }
        }
    }

    // ---- epilogue: transpose C tiles through LDS (smem[0] is free), then per-row ops ----
    float* rawS = &smem[0][0];         // 64 x 65 (padded)
    float* noiS = &smem[0][4160];      // 64 x 65
#pragma unroll
    for (int rt = 0; rt < 4; ++rt)
#pragma unroll
        for (int cc = 0; cc < 2; ++cc) {
            const int colg = (2 * w + cc) * 16 + c4;   // 0..127; <64 -> raw, else noise
            float* basep = (colg < NE) ? rawS : noiS;
            const int col = colg & 63;
#pragma unroll
            for (int v = 0; v < 4; ++v) {
                const int row = rt * 16 + q * 4 + v;   // C/D: col=lane&15, row=quad*4+reg
                basep[row * 65 + col] = acc[rt][cc][v];
            }
        }
    __syncthreads();

    const float br_l = br[lane];
    const float bn_l = bn[lane];
    float imp_acc = 0.f, load_acc = 0.f;
    float* out_em   = out;
    float* out_rp   = out + (size_t)N_TOK * NE;
    float* out_imp  = out + (size_t)2 * N_TOK * NE;
    float* out_load = out_imp + NE;

#pragma unroll 1
    for (int r = 0; r < 16; ++r) {
        const int lrow = w * 16 + r;
        const int row  = row0 + lrow;
        const float raw = rawS[lrow * 65 + lane] + br_l;
        const float nl  = noiS[lrow * 65 + lane] + bn_l;
        const float sd = fmaxf(nl, 0.f) + log1pf(expf(-fabsf(nl))) + 0.01f;
        const float epsv = noise_eps[(size_t)row * NE + lane];
        const float gum  = gumbel  [(size_t)row * NE + lane];
        const float noisy = fmaf(epsv, sd, raw);

        float cur = noisy;
        float thr = 0.f, m0 = 0.f;
#pragma unroll 1
        for (int k = 0; k < TOPK; ++k) {
            const float m = wave_max64(cur);
            if (k == 0) m0 = m;
            thr = m;
            const unsigned long long bm = __ballot(cur == m);
            const int first = __ffsll(bm) - 1;
            if (lane == first) cur = -INFINITY;
        }
        const float hard = (noisy >= thr) ? 1.f : 0.f;

        const float g  = noisy + gum;
        const float eg = expf(g - wave_max64(g));
        const float ms = eg / wave_sum64(eg);
        const float em = (hard - ms) + ms;

        const float en = expf(noisy - m0);
        const float rp = en / wave_sum64(en);

        const float er = expf(raw - wave_max64(raw));
        imp_acc += er / wave_sum64(er);

        const float z = (thr - raw) / sd;
        load_acc += 0.5f * erfcf(z * 45.254833995939045f);

        out_em[(size_t)row * NE + lane] = em;
        out_rp[(size_t)row * NE + lane] = rp;
    }

    float* red = &smem[1][0];          // smem[1] free in epilogue
    red[w * 64 + lane]       = imp_acc;
    red[256 + w * 64 + lane] = load_acc;
    __syncthreads();
    if (w == 0) {
        const float s1 = red[lane] + red[64 + lane] + red[128 + lane] + red[192 + lane];
        const float s2 = red[256 + lane] + red[320 + lane] + red[384 + lane] + red[448 + lane];
        atomicAdd(&out_imp[lane], s1);
        atomicAdd(&out_load[lane], s2);
    }
}

extern "C" void kernel_launch(void* const* d_in, const int* in_sizes, int n_in,
                              void* d_out, int out_size, void* d_ws, size_t ws_size,
                              hipStream_t stream)
{
    const float* x         = (const float*)d_in[0];
    const float* Wr        = (const float*)d_in[1];
    const float* br        = (const float*)d_in[2];
    const float* Wn        = (const float*)d_in[3];
    const float* bn        = (const float*)d_in[4];
    const float* noise_eps = (const float*)d_in[5];
    const float* gumbel    = (const float*)d_in[6];
    float* out = (float*)d_out;
    ushort_t* wsW = (ushort_t*)d_ws;   // needs 1 MB (64*8*2 slots * 1 KB)

    (void)hipMemsetAsync((char*)d_out + (size_t)2 * N_TOK * NE * sizeof(float), 0,
                         2 * NE * sizeof(float), stream);
    prep_w<<<1024, 256, 0, stream>>>(Wr, Wn, wsW);
    moe_main<<<N_TOK / ROWS, NTHREADS, 0, stream>>>(
        x, br, bn, noise_eps, gumbel, wsW, out);
}

// Round 5
// 266.908 us; speedup vs baseline: 1.8583x; 1.0470x over previous
//
#include <hip/hip_runtime.h>
#include <hip/hip_bf16.h>
#include <math.h>

#define N_TOK 16384
#define DIM   2048
#define NE    64
#define TOPK  9

#define ROWS     32            // rows per block
#define DC       64            // k-elements per chunk
#define NCHUNK   (DIM / DC)    // 32
#define NTHREADS 256           // 4 waves

typedef short  short8  __attribute__((ext_vector_type(8)));
typedef float  float4_ __attribute__((ext_vector_type(4)));
typedef unsigned short ushort_t;

__device__ __forceinline__ void async16(const void* g, void* l) {
    __builtin_amdgcn_global_load_lds(
        (const __attribute__((address_space(1))) void*)g,
        (__attribute__((address_space(3))) void*)l, 16, 0, 0);
}

__device__ __forceinline__ unsigned pk2(float a, float b) {
    float2 f; f.x = a; f.y = b;
    __hip_bfloat162 h = __float22bfloat162_rn(f);   // low16 = bf16(a)
    unsigned u;
    __builtin_memcpy(&u, &h, 4);
    return u;
}

// 8 fp32 -> bf16 hi frag + bf16 lo frag (2-term split)
__device__ __forceinline__ void cvt8(const float4_ va, const float4_ vb,
                                     short8* h, short8* l) {
    union { short8 s; unsigned u[4]; } H, L;
    const float f[8] = {va[0], va[1], va[2], va[3], vb[0], vb[1], vb[2], vb[3]};
#pragma unroll
    for (int i = 0; i < 4; ++i) {
        const float a = f[2 * i], b = f[2 * i + 1];
        const unsigned p = pk2(a, b);
        H.u[i] = p;
        const float ha = __uint_as_float(p << 16);
        const float hb = __uint_as_float(p & 0xffff0000u);
        L.u[i] = pk2(a - ha, b - hb);
    }
    *h = H.s; *l = L.s;
}

__device__ __forceinline__ float wave_max64(float v) {
#pragma unroll
    for (int off = 32; off > 0; off >>= 1)
        v = fmaxf(v, __shfl_xor(v, off, 64));
    return v;
}
__device__ __forceinline__ float wave_sum64(float v) {
#pragma unroll
    for (int off = 32; off > 0; off >>= 1)
        v += __shfl_xor(v, off, 64);
    return v;
}

// ---- prep: Wr|Wn (fp32, D x 64 each) -> B-fragment-ordered bf16 hi/lo ----
// slot s=(kcg*8+ct)*2+t holds 512 bf16: elem l*8+j = B[k=kcg*32+(l>>4)*8+j][n=ct*16+(l&15)]
// thread per (kcg, ct, l): 8 strided reads, two coalesced 16B writes
__global__ __launch_bounds__(256)
void prep_w(const float* __restrict__ Wr, const float* __restrict__ Wn,
            ushort_t* __restrict__ wsW)
{
    const int gid = blockIdx.x * 256 + threadIdx.x;   // [0, 64*8*64)
    const int l   = gid & 63;
    const int ct  = (gid >> 6) & 7;
    const int kcg = gid >> 9;                         // 0..63
    const int n   = ct * 16 + (l & 15);
    const int k0  = kcg * 32 + (l >> 4) * 8;
    const float* src = (n < NE) ? (Wr + n) : (Wn + (n - NE));
    union { short8 s; ushort_t us[8]; } H, L;
#pragma unroll
    for (int j = 0; j < 8; ++j) {
        const float v = src[(size_t)(k0 + j) * NE];
        const unsigned uv = __float_as_uint(v);
        const unsigned hb = (uv + 0x7fffu + ((uv >> 16) & 1u)) & 0xffff0000u;
        const float lo = v - __uint_as_float(hb);
        const unsigned ul = __float_as_uint(lo);
        H.us[j] = (ushort_t)(hb >> 16);
        L.us[j] = (ushort_t)((ul + 0x7fffu + ((ul >> 16) & 1u)) >> 16);
    }
    const size_t s0 = (size_t)(kcg * 8 + ct) * 2;     // slot pair index
    *(short8*)(wsW + s0 * 512 + l * 8)         = H.s;
    *(short8*)(wsW + (s0 + 1) * 512 + l * 8)   = L.s;
}

__global__ __launch_bounds__(NTHREADS, 3)
void moe_main(const float* __restrict__ x,
              const float* __restrict__ br,
              const float* __restrict__ bn,
              const float* __restrict__ noise_eps,
              const float* __restrict__ gumbel,
              const ushort_t* __restrict__ wsW,
              float* __restrict__ out)
{
    // stage: 2 x 2048 floats (x double-buffer, 16 KB); epilogue: 2 x 32 x 65 = 4160
    __shared__ __align__(16) float smem[4352];

    const int t    = threadIdx.x;
    const int lane = t & 63;
    const int w    = t >> 6;          // wave 0..3, owns col-tiles {2w, 2w+1}
    const int c4   = lane & 15;
    const int q    = lane >> 4;
    const int row0 = blockIdx.x * ROWS;

    // x staging: 8 issues per chunk (wave w does i=2w,2w+1); issue i covers rows 4i..4i+3
    // lane l -> row 4i+(l>>4); LDS granule pos p=l&15 holds global granule gk=p^(row&15)
    const float* gxp[2];
    int lxo[2];
#pragma unroll
    for (int ii = 0; ii < 2; ++ii) {
        const int i  = 2 * w + ii;
        const int r  = 4 * i + q;
        const int gk = c4 ^ (r & 15);
        gxp[ii] = x + (size_t)(row0 + r) * DIM + gk * 4;
        lxo[ii] = i * 256;            // float offset in stage buffer
    }

    // A-read offsets (chunk-invariant): row m=rt*16+c4, granules (kc*8+q*2)^c4, +1^c4
    int aoff[2][2];
#pragma unroll
    for (int kc = 0; kc < 2; ++kc) {
        const int g0 = kc * 8 + q * 2;
        aoff[kc][0] = c4 * 64 + ((g0 ^ c4) * 4);
        aoff[kc][1] = c4 * 64 + (((g0 + 1) ^ c4) * 4);
    }

    float4_ acc[2][2];
#pragma unroll
    for (int rt = 0; rt < 2; ++rt)
#pragma unroll
        for (int cc = 0; cc < 2; ++cc)
            acc[rt][cc] = (float4_)(0.f);

    const char* wsB = (const char*)wsW;

    // prologue: issue x chunk 0 into buf0
#pragma unroll
    for (int ii = 0; ii < 2; ++ii) { async16(gxp[ii], &smem[lxo[ii]]); gxp[ii] += DC; }

    for (int ch = 0; ch < NCHUNK; ++ch) {
        __syncthreads();               // drains vmcnt -> x chunk ch in LDS
        const int b = ch & 1;
        // B fragment loads FIRST (so their wait is vmcnt(2), not vmcnt(0))
        short8 bh[2][2], bl[2][2];
#pragma unroll
        for (int kc = 0; kc < 2; ++kc)
#pragma unroll
            for (int cc = 0; cc < 2; ++cc) {
                const size_t off = (size_t)(((ch * 2 + kc) * 8) + 2 * w + cc) * 2048 + lane * 16;
                bh[kc][cc] = *(const short8*)(wsB + off);
                bl[kc][cc] = *(const short8*)(wsB + off + 1024);
            }
        // then prefetch next x chunk into the freed buffer
        if (ch + 1 < NCHUNK) {
#pragma unroll
            for (int ii = 0; ii < 2; ++ii) {
                async16(gxp[ii], &smem[(b ^ 1) * 2048 + lxo[ii]]);
                gxp[ii] += DC;
            }
        }
        const float* xb = &smem[b * 2048];
#pragma unroll
        for (int kc = 0; kc < 2; ++kc)
#pragma unroll
            for (int rt = 0; rt < 2; ++rt) {
                const float4_ va = *(const float4_*)(xb + rt * 1024 + aoff[kc][0]);
                const float4_ vb = *(const float4_*)(xb + rt * 1024 + aoff[kc][1]);
                short8 ah, al;
                cvt8(va, vb, &ah, &al);
#pragma unroll
                for (int cc = 0; cc < 2; ++cc) {
                    acc[rt][cc] = __builtin_amdgcn_mfma_f32_16x16x32_bf16(ah, bh[kc][cc], acc[rt][cc], 0, 0, 0);
                    acc[rt][cc] = __builtin_amdgcn_mfma_f32_16x16x32_bf16(al, bh[kc][cc], acc[rt][cc], 0, 0, 0);
                    acc[rt][cc] = __builtin_amdgcn_mfma_f32_16x16x32_bf16(ah, bl[kc][cc], acc[rt][cc], 0, 0, 0);
                }
            }
    }

    // ---- epilogue: transpose C tiles through LDS, then per-row wave ops ----
    __syncthreads();                   // all A-reads of last chunk done
    float* rawS = &smem[0];            // 32 x 65 (padded)
    float* noiS = &smem[2080];         // 32 x 65
#pragma unroll
    for (int rt = 0; rt < 2; ++rt)
#pragma unroll
        for (int cc = 0; cc < 2; ++cc) {
            const int colg = (2 * w + cc) * 16 + c4;   // 0..127; <64 raw else noise
            float* basep = (colg < NE) ? rawS : noiS;
            const int col = colg & 63;
#pragma unroll
            for (int v = 0; v < 4; ++v) {
                const int row = rt * 16 + q * 4 + v;   // C/D: col=lane&15, row=quad*4+reg
                basep[row * 65 + col] = acc[rt][cc][v];
            }
        }
    __syncthreads();

    const float br_l = br[lane];
    const float bn_l = bn[lane];
    float imp_acc = 0.f, load_acc = 0.f;
    float* out_em   = out;
    float* out_rp   = out + (size_t)N_TOK * NE;
    float* out_imp  = out + (size_t)2 * N_TOK * NE;
    float* out_load = out_imp + NE;

#pragma unroll 1
    for (int r = 0; r < 8; ++r) {
        const int lrow = w * 8 + r;
        const int row  = row0 + lrow;
        const float raw = rawS[lrow * 65 + lane] + br_l;
        const float nl  = noiS[lrow * 65 + lane] + bn_l;
        const float sd = fmaxf(nl, 0.f) + log1pf(expf(-fabsf(nl))) + 0.01f;
        const float epsv = noise_eps[(size_t)row * NE + lane];
        const float gum  = gumbel  [(size_t)row * NE + lane];
        const float noisy = fmaf(epsv, sd, raw);

        float cur = noisy;
        float thr = 0.f, m0 = 0.f;
#pragma unroll 1
        for (int k = 0; k < TOPK; ++k) {
            const float m = wave_max64(cur);
            if (k == 0) m0 = m;
            thr = m;
            const unsigned long long bm = __ballot(cur == m);
            const int first = __ffsll(bm) - 1;
            if (lane == first) cur = -INFINITY;
        }
        const float hard = (noisy >= thr) ? 1.f : 0.f;

        const float g  = noisy + gum;
        const float eg = expf(g - wave_max64(g));
        const float ms = eg / wave_sum64(eg);
        const float em = (hard - ms) + ms;

        const float en = expf(noisy - m0);
        const float rp = en / wave_sum64(en);

        const float er = expf(raw - wave_max64(raw));
        imp_acc += er / wave_sum64(er);

        const float z = (thr - raw) / sd;
        load_acc += 0.5f * erfcf(z * 45.254833995939045f);

        out_em[(size_t)row * NE + lane] = em;
        out_rp[(size_t)row * NE + lane] = rp;
    }

    __syncthreads();                   // rawS/noiS reads done; reuse for reduction
    smem[w * 64 + lane]       = imp_acc;
    smem[256 + w * 64 + lane] = load_acc;
    __syncthreads();
    if (w == 0) {
        const float s1 = smem[lane] + smem[64 + lane] + smem[128 + lane] + smem[192 + lane];
        const float s2 = smem[256 + lane] + smem[320 + lane] + smem[384 + lane] + smem[448 + lane];
        atomicAdd(&out_imp[lane], s1);
        atomicAdd(&out_load[lane], s2);
    }
}

extern "C" void kernel_launch(void* const* d_in, const int* in_sizes, int n_in,
                              void* d_out, int out_size, void* d_ws, size_t ws_size,
                              hipStream_t stream)
{
    const float* x         = (const float*)d_in[0];
    const float* Wr        = (const float*)d_in[1];
    const float* br        = (const float*)d_in[2];
    const float* Wn        = (const float*)d_in[3];
    const float* bn        = (const float*)d_in[4];
    const float* noise_eps = (const float*)d_in[5];
    const float* gumbel    = (const float*)d_in[6];
    float* out = (float*)d_out;
    ushort_t* wsW = (ushort_t*)d_ws;   // 1 MB (64*8*2 slots x 1 KB)

    (void)hipMemsetAsync((char*)d_out + (size_t)2 * N_TOK * NE * sizeof(float), 0,
                         2 * NE * sizeof(float), stream);
    prep_w<<<128, 256, 0, stream>>>(Wr, Wn, wsW);
    moe_main<<<N_TOK / ROWS, NTHREADS, 0, stream>>>(
        x, br, bn, noise_eps, gumbel, wsW, out);
}